// Round 12
// baseline (399.172 us; speedup 1.0000x reference)
//
#include <hip/hip_runtime.h>

#define B_    4096
#define H_    1024
#define NLAY  4

typedef __attribute__((ext_vector_type(8))) short bf16x8;
typedef __attribute__((ext_vector_type(4))) short s16x4;
typedef __attribute__((ext_vector_type(4))) float f32x4;
typedef unsigned short ushort_t;

__device__ __forceinline__ ushort_t f2bf(float f) {
  unsigned u = __builtin_bit_cast(unsigned, f);
  u += 0x7FFFu + ((u >> 16) & 1u);
  return (ushort_t)(u >> 16);
}

__device__ __forceinline__ float fast_sigmoid(float x) {
  float e = __expf(-fabsf(x));
  float s = 1.0f / (1.0f + e);
  return x >= 0.0f ? s : 1.0f - s;
}
__device__ __forceinline__ float fast_tanh(float x) {
  float e = __expf(-2.0f * fabsf(x));
  float t = (1.0f - e) / (1.0f + e);
  return x >= 0.0f ? t : -t;
}

#define GLDS16(gsrc, ldst)                                                  \
  __builtin_amdgcn_global_load_lds(                                         \
      (__attribute__((address_space(1))) void*)(gsrc),                      \
      (__attribute__((address_space(3))) void*)(ldst), 16, 0, 0)

#define BAR()                                                               \
  { asm volatile("" ::: "memory");                                          \
    __builtin_amdgcn_s_barrier();                                           \
    asm volatile("" ::: "memory"); }

#define WAITV(N)                                                            \
  { asm volatile("s_waitcnt vmcnt(" #N ")" ::: "memory");                   \
    __builtin_amdgcn_sched_barrier(0); }

#define LGKM0()                                                             \
  { asm volatile("s_waitcnt lgkmcnt(0)" ::: "memory");                      \
    __builtin_amdgcn_sched_barrier(0); }

__device__ __forceinline__ bf16x8 dsr128(unsigned addr, int imm) {
  bf16x8 r;
  asm volatile("ds_read_b128 %0, %1 offset:%c2"
               : "=v"(r)
               : "v"(addr), "i"(imm));
  return r;
}

// MFMA with the accumulator pinned to AGPRs — frees the arch-VGPR file so
// the 256-f32 accumulator of a 128x128 wave tile does not spill.
__device__ __forceinline__ void mfma_a(f32x4& d, bf16x8 a, bf16x8 b) {
  asm volatile("v_mfma_f32_16x16x32_bf16 %0, %1, %2, %0"
               : "+a"(d)
               : "v"(a), "v"(b));
}

__device__ __forceinline__ int swz(int row, int kelem) {
  return ((row * 64 + kelem) * 2) ^ ((row & 7) << 4);
}

// ---------------------------------------------------------------------------
// 4-wave big-accumulator fused LSTM layer (R8 design, AGPR-fixed).
// Block: 256 thr = 4 waves (2M x 2N), wave tile 128 rows x 128 packed cols,
// acc[8][8] f32x4 = 256 AGPR/wave (asm "+a"), ~160 VGPR, 1 wave/SIMD.
// BM=256 x BN=256 packed gate-cols, BK=64, 32 K-tiles, grid 256 (1 blk/CU).
// Packed col p: wave wn owns p = wn*128 + g*32 + hg*16 + hc
//   -> gate col g*1024 + bn*64 + wn*32 + hg*16 + hc.
// LDS 128 KB: A[par][rowhalf] 4x16KB @0, B[par][pcolhalf] 4x16KB @64K.
// Half image 16 KB = [kh 2][r 128][slot 4]x16B, slot s holds octet
// o = s^((r>>1)&3). Per-CU LDS read/tile = 128 KB (vs 192 in the 8-wave
// variants) -> LDS-read 1506 cyc < MFMA 2480 cyc.
// ---------------------------------------------------------------------------
__global__ __launch_bounds__(256, 1) void lstm8(
    const ushort_t* __restrict__ aX, const ushort_t* __restrict__ aH,
    const float* __restrict__ cprev, const float* __restrict__ bi,
    const float* __restrict__ bh, const ushort_t* __restrict__ wtl,
    float* __restrict__ hout, float* __restrict__ cout,
    ushort_t* __restrict__ hbfout) {
  __shared__ __align__(16) char sL[131072];

  const int tid  = threadIdx.x;
  const int lane = tid & 63;
  const int wid  = tid >> 6;      // 0..3
  const int wm   = wid >> 1;      // 0..1
  const int wn   = wid & 1;       // 0..1
  // XCD-aware: each XCD owns an 8bm x 4bn sub-grid
  const int xcd = blockIdx.x & 7, bj = blockIdx.x >> 3;
  const int bm  = (xcd >> 2) * 8 + (bj >> 2);
  const int bn  = (xcd & 3) * 4 + (bj & 3);

  const int fr = lane & 15;
  const int oF = lane >> 4;
  const int sw = (oF ^ ((fr >> 1) & 3)) * 16;

  const unsigned sBase = (unsigned)(size_t)&sL[0];
  const unsigned aAddr = sBase + (unsigned)(wm * 16384 + fr * 64 + sw);
  const unsigned bAddr = sBase + (unsigned)(65536 + wn * 16384 + fr * 64 + sw);

  // A-staging source element-offsets for the 4 chunks (c = 0..3)
  int aof[4];
#pragma unroll
  for (int c = 0; c < 4; ++c) {
    const int q = tid + c * 256;
    const int kh = q >> 9, r = (q >> 2) & 127, s = q & 3;
    const int o = s ^ ((r >> 1) & 3);
    aof[c] = r * 1024 + kh * 32 + o * 8;
  }
  const int aof0 = aof[0], aof1 = aof[1], aof2 = aof[2], aof3 = aof[3];
  const size_t aRowBase = (size_t)(bm * 256) * 1024;
  const ushort_t* wtBn = wtl + (size_t)bn * 524288;   // 32 tiles * 16384

  f32x4 acc[8][8];
#pragma unroll
  for (int m = 0; m < 8; ++m)
#pragma unroll
    for (int n = 0; n < 8; ++n) acc[m][n] = (f32x4){0.f, 0.f, 0.f, 0.f};

  bf16x8 ar[4][2], br0[4][2], br1[4][2];

#define STAGE_A(PAR, HALF, TT)                                               \
  {                                                                          \
    const ushort_t* bp = (((TT) < 16) ? aX : aH) + aRowBase +                \
                         (HALF) * 131072 + ((TT) & 15) * 64;                 \
    char* d = sL + (PAR) * 32768 + (HALF) * 16384 + wid * 1024;              \
    GLDS16(bp + aof0, d);                                                    \
    GLDS16(bp + aof1, d + 4096);                                             \
    GLDS16(bp + aof2, d + 8192);                                             \
    GLDS16(bp + aof3, d + 12288);                                            \
  }
#define STAGE_B(PAR, HALF, TT)                                               \
  {                                                                          \
    const ushort_t* bp =                                                     \
        wtBn + (size_t)(TT) * 16384 + (HALF) * 8192 + tid * 8;               \
    char* d = sL + 65536 + (PAR) * 32768 + (HALF) * 16384 + wid * 1024;      \
    GLDS16(bp, d);                                                           \
    GLDS16(bp + 2048, d + 4096);                                             \
    GLDS16(bp + 4096, d + 8192);                                             \
    GLDS16(bp + 6144, d + 12288);                                            \
  }
#define RD_A(PAR, MH)                                                        \
  _Pragma("unroll") for (int mp = 0; mp < 4; ++mp)                           \
      _Pragma("unroll") for (int kh = 0; kh < 2; ++kh)                       \
      ar[mp][kh] = dsr128(aAddr, (PAR) * 32768 + kh * 8192 +                 \
                                     ((MH) * 4 + mp) * 1024);
#define RD_B(PAR, NH, BR)                                                    \
  _Pragma("unroll") for (int gg = 0; gg < 4; ++gg)                           \
      _Pragma("unroll") for (int kh = 0; kh < 2; ++kh)                       \
      BR[gg][kh] = dsr128(bAddr, (PAR) * 32768 + kh * 8192 +                 \
                                     ((NH) * 4 + gg) * 1024);
#define MM(MH, NH, BR)                                                       \
  _Pragma("unroll") for (int gg = 0; gg < 4; ++gg)                           \
      _Pragma("unroll") for (int mp = 0; mp < 4; ++mp)                       \
      _Pragma("unroll") for (int kh = 0; kh < 2; ++kh)                       \
      mfma_a(acc[(MH) * 4 + mp][(NH) * 4 + gg], ar[mp][kh], BR[gg][kh]);

  // ---- prologue ----
  STAGE_A(0, 0, 0)
  STAGE_A(0, 1, 0)
  STAGE_B(0, 0, 0)
  STAGE_B(0, 1, 0)
  STAGE_B(1, 0, 1)
  STAGE_B(1, 1, 1)
  WAITV(8)
  BAR()

#pragma unroll 1
  for (int t2 = 0; t2 < 32; t2 += 2) {
    // ---- tile T = t2 (par 0) ----
    RD_A(0, 0) RD_B(0, 0, br0)
    STAGE_A(1, 0, t2 + 1)
    BAR()
    LGKM0()
    MM(0, 0, br0)
    BAR()

    RD_B(0, 1, br1)
    STAGE_A(1, 1, t2 + 1)
    BAR()
    LGKM0()
    MM(0, 1, br1)
    BAR()

    RD_A(0, 1)
    STAGE_B(0, 0, t2 + 2)
    BAR()
    LGKM0()
    MM(1, 0, br0)
    BAR()

    STAGE_B(0, 1, t2 + 2)
    BAR()
    MM(1, 1, br1)
    WAITV(8)
    BAR()

    // ---- tile T+1 (par 1) ----
    RD_A(1, 0) RD_B(1, 0, br0)
    STAGE_A(0, 0, t2 + 2)
    BAR()
    LGKM0()
    MM(0, 0, br0)
    BAR()

    RD_B(1, 1, br1)
    STAGE_A(0, 1, t2 + 2)
    BAR()
    LGKM0()
    MM(0, 1, br1)
    BAR()

    RD_A(1, 1)
    STAGE_B(1, 0, t2 + 3)
    BAR()
    LGKM0()
    MM(1, 0, br0)
    BAR()

    STAGE_B(1, 1, t2 + 3)
    BAR()
    MM(1, 1, br1)
    WAITV(8)
    BAR()
  }
#undef STAGE_A
#undef STAGE_B
#undef RD_A
#undef RD_B
#undef MM

  WAITV(0)
  __syncthreads();

  // ---- epilogue: LSTM cell + coalesced I/O via padded LDS bounce ----
  float bsum[2][4];
#pragma unroll
  for (int hg = 0; hg < 2; ++hg)
#pragma unroll
    for (int g = 0; g < 4; ++g) {
      const int col = g * 1024 + bn * 64 + wn * 32 + hg * 16 + fr;
      bsum[hg][g] = bi[col] + bh[col];
    }

#define LSTRIDE 68
  float* LF = (float*)sL;                      // 256 x 68 fp32
  const int crow = tid >> 4;                   // 0..15
  const int cc4  = (tid & 15) * 4;
  {
    const float* cp0 = cprev + (size_t)(bm * 256) * 1024 + bn * 64;
#pragma unroll
    for (int i = 0; i < 16; ++i) {
      const int row = i * 16 + crow;
      f32x4 v = *(const f32x4*)(cp0 + (size_t)row * 1024 + cc4);
      *(f32x4*)(LF + row * LSTRIDE + cc4) = v;
    }
  }
  __syncthreads();
  float hv[8][2][4];
#pragma unroll
  for (int m = 0; m < 8; ++m) {
    const int rowb = wm * 128 + m * 16 + oF * 4;
#pragma unroll
    for (int hg = 0; hg < 2; ++hg) {
      const int hc = wn * 32 + hg * 16 + fr;
#pragma unroll
      for (int r = 0; r < 4; ++r) {
        const float cp = LF[(rowb + r) * LSTRIDE + hc];
        const float gi = fast_sigmoid(acc[m][0 + hg][r] + bsum[hg][0]);
        const float gf = fast_sigmoid(acc[m][2 + hg][r] + bsum[hg][1]);
        const float gg = fast_tanh(acc[m][4 + hg][r] + bsum[hg][2]);
        const float go = fast_sigmoid(acc[m][6 + hg][r] + bsum[hg][3]);
        const float c  = gf * cp + gi * gg;
        LF[(rowb + r) * LSTRIDE + hc] = c;       // owner-exclusive cell
        hv[m][hg][r] = go * fast_tanh(c);
      }
    }
  }
  __syncthreads();
  {
    float* co0 = cout + (size_t)(bm * 256) * 1024 + bn * 64;
#pragma unroll
    for (int i = 0; i < 16; ++i) {
      const int row = i * 16 + crow;
      f32x4 v = *(const f32x4*)(LF + row * LSTRIDE + cc4);
      *(f32x4*)(co0 + (size_t)row * 1024 + cc4) = v;
    }
  }
  __syncthreads();
#pragma unroll
  for (int m = 0; m < 8; ++m) {
    const int rowb = wm * 128 + m * 16 + oF * 4;
#pragma unroll
    for (int hg = 0; hg < 2; ++hg) {
      const int hc = wn * 32 + hg * 16 + fr;
#pragma unroll
      for (int r = 0; r < 4; ++r) LF[(rowb + r) * LSTRIDE + hc] = hv[m][hg][r];
    }
  }
  __syncthreads();
  {
    float* ho0 = hout + (size_t)(bm * 256) * 1024 + bn * 64;
    ushort_t* hb0 = hbfout + (size_t)(bm * 256) * 1024 + bn * 64;
#pragma unroll
    for (int i = 0; i < 16; ++i) {
      const int row = i * 16 + crow;
      f32x4 v = *(const f32x4*)(LF + row * LSTRIDE + cc4);
      *(f32x4*)(ho0 + (size_t)row * 1024 + cc4) = v;
      s16x4 hb;
#pragma unroll
      for (int j = 0; j < 4; ++j) hb[j] = (short)f2bf(v[j]);
      *(s16x4*)(hb0 + (size_t)row * 1024 + cc4) = hb;
    }
  }
#undef LSTRIDE
}

// ---------------------------------------------------------------------------
// Weight pack (z=0..3, R8 image format) + fc transpose (z=4, first 16 Ts).
// Image per (l, bn, T): 32 KB, chunk idx = half*1024 + kh*512 + r*4 + s,
// octet o = s^((r>>1)&3), k = T*64 + kh*32 + o*8 + j,
// p = half*128 + r -> gatecol = g*1024 + bn*64 + wn*32 + hg*16 + hc
// with wn=p>>7, g=(p&127)>>5, hg=(p>>4)&1, hc=p&15.
// ---------------------------------------------------------------------------
__global__ __launch_bounds__(512) void packW(const float* __restrict__ Wi,
                                             const float* __restrict__ Wh,
                                             const float* __restrict__ Wfc,
                                             ushort_t* __restrict__ wt,
                                             ushort_t* __restrict__ fcwt) {
  const int bn = blockIdx.x;   // 0..15
  const int T  = blockIdx.y;   // 0..31
  const int l  = blockIdx.z;   // 0..4
  const int tid = threadIdx.x;

  if (l == 4) {                // fc transpose plane
    if (T >= 16) return;
    const int c  = tid & 63;
    const int ko = (tid >> 6) * 8;
    float v[8];
#pragma unroll
    for (int j = 0; j < 8; ++j)
      v[j] = Wfc[(size_t)(T * 64 + ko + j) * 1024 + bn * 64 + c];
    bf16x8 o;
#pragma unroll
    for (int j = 0; j < 8; ++j) o[j] = (short)f2bf(v[j]);
    ushort_t* tile = fcwt + ((size_t)bn * 16 + T) * 4096;
    *(bf16x8*)((char*)tile + swz(c, ko)) = o;
    return;
  }

  __shared__ ushort_t t16[64 * 257];
  const int kq = tid >> 6, cc = tid & 63;
  const int k0 = T * 64;
  const float* W = (k0 < 1024)
                       ? (Wi + (size_t)l * 1024 * 4096 + (size_t)k0 * 4096)
                       : (Wh + (size_t)l * 1024 * 4096 + (size_t)(k0 - 1024) * 4096);
#pragma unroll
  for (int kk = 0; kk < 8; ++kk) {
    const int kl = kq * 8 + kk;
#pragma unroll
    for (int g = 0; g < 4; ++g) {
      const float v = W[(size_t)kl * 4096 + g * 1024 + bn * 64 + cc];
      const int p = (cc >> 5) * 128 + g * 32 + ((cc >> 4) & 1) * 16 + (cc & 15);
      t16[kl * 257 + p] = f2bf(v);
    }
  }
  __syncthreads();
  ushort_t* tile = wt + (((size_t)l * 16 + bn) * 32 + T) * 16384;
#pragma unroll
  for (int c = 0; c < 4; ++c) {
    const int idx = c * 512 + tid;          // chunk 0..2047
    const int half = idx >> 10;
    const int kh = (idx >> 9) & 1;
    const int r  = (idx >> 2) & 127;
    const int s  = idx & 3;
    const int o  = s ^ ((r >> 1) & 3);
    const int klb = kh * 32 + o * 8;
    const int p   = half * 128 + r;
    bf16x8 ov;
#pragma unroll
    for (int j = 0; j < 8; ++j) ov[j] = (short)t16[(klb + j) * 257 + p];
    *(bf16x8*)(tile + (size_t)idx * 8) = ov;
  }
}

// ---------------------------------------------------------------------------
// FC: y = h3 @ fc_W + fc_b — triple-buffered, counted vmcnt (R11).
// ---------------------------------------------------------------------------
__global__ __launch_bounds__(512) void fc_kernel(
    const ushort_t* __restrict__ wtfc, const ushort_t* __restrict__ abf,
    const float* __restrict__ bias, float* __restrict__ y) {
  __shared__ __align__(16) char sA[3][16384];
  __shared__ __align__(16) char sB[3][8192];
  const int tid  = threadIdx.x;
  const int lane = tid & 63;
  const int wid  = tid >> 6;
  const int wm   = wid >> 2;
  const int wn   = wid & 3;
  const int bid  = (blockIdx.x & 7) * 64 + (blockIdx.x >> 3);
  const int bm   = bid & 31;
  const int bn   = bid >> 5;

  f32x4 acc[4];
#pragma unroll
  for (int m = 0; m < 4; ++m) acc[m] = (f32x4){0.f, 0.f, 0.f, 0.f};

  const int rloc = wid * 8 + (lane >> 3);
  const int jA   = (lane & 7) ^ ((lane >> 3) & 7);
  const ushort_t* aSrc = abf + (size_t)(bm * 128 + rloc) * 1024 + jA * 8;

#define FSTAGE(BUF, KS)                                                      \
  {                                                                          \
    GLDS16(wtfc + (size_t)(bn * 16 + (KS)) * 4096 + tid * 8,                 \
           sB[BUF] + wid * 1024);                                            \
    GLDS16(aSrc + (KS) * 64, sA[BUF] + wid * 1024);                          \
    GLDS16(aSrc + (KS) * 64 + 64 * 1024, sA[BUF] + 8192 + wid * 1024);       \
  }

  FSTAGE(0, 0)
  FSTAGE(1, 1)
  WAITV(3)
  BAR()

#pragma unroll
  for (int ks = 0; ks < 16; ++ks) {
    const int cur = ks % 3;
    if (ks + 2 < 16) { FSTAGE((ks + 2) % 3, ks + 2) }
#pragma unroll
    for (int kk = 0; kk < 64; kk += 32) {
      const int ke = kk + (lane >> 4) * 8;
      bf16x8 a[4];
#pragma unroll
      for (int m = 0; m < 4; ++m)
        a[m] = *(const bf16x8*)(sA[cur] +
                                swz(wm * 64 + m * 16 + (lane & 15), ke));
      bf16x8 b = *(const bf16x8*)(sB[cur] + swz(wn * 16 + (lane & 15), ke));
#pragma unroll
      for (int m = 0; m < 4; ++m)
        acc[m] = __builtin_amdgcn_mfma_f32_16x16x32_bf16(a[m], b, acc[m], 0, 0, 0);
    }
    if (ks < 15) {
      if (ks + 2 < 16) { WAITV(3) } else { WAITV(0) }
      BAR()
    }
  }
#undef FSTAGE

  const int col = bn * 64 + wn * 16 + (lane & 15);
  const float bb = bias[col];
#pragma unroll
  for (int m = 0; m < 4; ++m) {
    const int row0 = bm * 128 + wm * 64 + m * 16 + ((lane >> 4) << 2);
#pragma unroll
    for (int r = 0; r < 4; ++r)
      y[(size_t)(row0 + r) * 1024 + col] = acc[m][r] + bb;
  }
}

// fp32 -> bf16 bulk convert for x and hprev in one launch
__global__ __launch_bounds__(256) void cvt_bf16_2(const float* __restrict__ s0,
                                                  unsigned n0,
                                                  const float* __restrict__ s1,
                                                  ushort_t* __restrict__ d0,
                                                  ushort_t* __restrict__ d1,
                                                  unsigned ntot) {
  const unsigned i = blockIdx.x * 256 + threadIdx.x;
  if (i >= ntot) return;
  const float* p;
  ushort_t* d;
  unsigned j;
  if (i < n0) {
    p = s0; d = d0; j = i;
  } else {
    p = s1; d = d1; j = i - n0;
  }
  const float* pp = p + (size_t)j * 8;
  f32x4 a = ((const f32x4*)pp)[0];
  f32x4 b = ((const f32x4*)pp)[1];
  bf16x8 o;
#pragma unroll
  for (int k = 0; k < 4; ++k) {
    o[k]     = (short)f2bf(a[k]);
    o[4 + k] = (short)f2bf(b[k]);
  }
  *(bf16x8*)(d + (size_t)j * 8) = o;
}

extern "C" void kernel_launch(void* const* d_in, const int* in_sizes, int n_in,
                              void* d_out, int out_size, void* d_ws,
                              size_t ws_size, hipStream_t stream) {
  const float* x     = (const float*)d_in[0];
  const float* hprev = (const float*)d_in[1];
  const float* cprev = (const float*)d_in[2];
  const float* Wi    = (const float*)d_in[3];
  const float* Wh    = (const float*)d_in[4];
  const float* bi    = (const float*)d_in[5];
  const float* bh    = (const float*)d_in[6];
  const float* fcW   = (const float*)d_in[7];
  const float* fcb   = (const float*)d_in[8];

  float* out = (float*)d_out;
  const size_t BH = (size_t)B_ * H_;          // 4194304
  float* y    = out;
  float* hout = out + BH;
  float* cout = out + 5 * BH;

  const size_t WT_ELEMS = (size_t)4 * 16 * 32 * 16384;  // 33554432
  const size_t FC_ELEMS = (size_t)16 * 16 * 4096;       // 1048576
  ushort_t* wt      = (ushort_t*)d_ws;
  ushort_t* fcwt    = wt + WT_ELEMS;
  ushort_t* xbf     = fcwt + FC_ELEMS;
  ushort_t* hprevbf = xbf + BH;
  ushort_t* houtbf  = hprevbf + 4 * BH;

  packW<<<dim3(16, 32, 5), dim3(512), 0, stream>>>(Wi, Wh, fcW, wt, fcwt);
  {
    const unsigned n0 = (unsigned)(BH / 8);          // x chunks
    const unsigned n1 = (unsigned)(4 * BH / 8);      // hprev chunks
    const unsigned nt = n0 + n1;
    cvt_bf16_2<<<dim3((nt + 255) / 256), dim3(256), 0, stream>>>(
        x, n0, hprev, xbf, hprevbf, nt);
  }

  for (int l = 0; l < NLAY; ++l) {
    const ushort_t* aX  = (l == 0) ? xbf : (houtbf + (size_t)(l - 1) * BH);
    const ushort_t* wtl = wt + (size_t)l * 16 * 32 * 16384;
    lstm8<<<dim3(256), dim3(256), 0, stream>>>(
        aX, hprevbf + (size_t)l * BH, cprev + (size_t)l * BH, bi + l * 4096,
        bh + l * 4096, wtl, hout + (size_t)l * BH, cout + (size_t)l * BH,
        houtbf + (size_t)l * BH);
  }
  fc_kernel<<<dim3(512), dim3(512), 0, stream>>>(fcwt, houtbf + 3 * BH, fcb, y);
}

// Round 13
// 370.307 us; speedup vs baseline: 1.0779x; 1.0779x over previous
//
#include <hip/hip_runtime.h>

#define B_    4096
#define H_    1024
#define NLAY  4

typedef __attribute__((ext_vector_type(8))) short bf16x8;
typedef __attribute__((ext_vector_type(4))) short s16x4;
typedef __attribute__((ext_vector_type(4))) float f32x4;
typedef unsigned short ushort_t;

__device__ __forceinline__ ushort_t f2bf(float f) {
  unsigned u = __builtin_bit_cast(unsigned, f);
  u += 0x7FFFu + ((u >> 16) & 1u);
  return (ushort_t)(u >> 16);
}

__device__ __forceinline__ float fast_sigmoid(float x) {
  float e = __expf(-fabsf(x));
  float s = 1.0f / (1.0f + e);
  return x >= 0.0f ? s : 1.0f - s;
}
__device__ __forceinline__ float fast_tanh(float x) {
  float e = __expf(-2.0f * fabsf(x));
  float t = (1.0f - e) / (1.0f + e);
  return x >= 0.0f ? t : -t;
}

#define GLDS16(gsrc, ldst)                                                  \
  __builtin_amdgcn_global_load_lds(                                         \
      (__attribute__((address_space(1))) void*)(gsrc),                      \
      (__attribute__((address_space(3))) void*)(ldst), 16, 0, 0)

#define BAR()                                                               \
  { asm volatile("" ::: "memory");                                          \
    __builtin_amdgcn_s_barrier();                                           \
    asm volatile("" ::: "memory"); }

#define WAITV(N)                                                            \
  { asm volatile("s_waitcnt vmcnt(" #N ")" ::: "memory");                   \
    __builtin_amdgcn_sched_barrier(0); }

#define LGKM0()                                                             \
  { asm volatile("s_waitcnt lgkmcnt(0)" ::: "memory");                      \
    __builtin_amdgcn_sched_barrier(0); }

__device__ __forceinline__ bf16x8 dsr128(unsigned addr, int imm) {
  bf16x8 r;
  asm volatile("ds_read_b128 %0, %1 offset:%c2"
               : "=v"(r)
               : "v"(addr), "i"(imm));
  return r;
}

__device__ __forceinline__ int swz(int row, int kelem) {
  return ((row * 64 + kelem) * 2) ^ ((row & 7) << 4);
}

// ---------------------------------------------------------------------------
// m201-style 8-phase fused LSTM layer (R7 K-loop, frozen; R10 tail: final
// tile-pair's prefetch slots stage the 64 KB fp32 cprev tile into dying
// A[par0]/B[par0] LDS buffers; epilogue computes the cell from the in-LDS
// cprev image — no serial global read, 3 barriers).
// cprev image: global row R (0..255), col c (0..63):
//   byte = QBASE(R>>6) + (R&63)*256 + c*4,
//   QBASE = {65536, 81920, 0, 16384}  (q0,q1 -> B[par0]; q2,q3 -> A[par0]).
// ---------------------------------------------------------------------------
__global__ __launch_bounds__(512, 2) void lstm8(
    const ushort_t* __restrict__ aX, const ushort_t* __restrict__ aH,
    const float* __restrict__ cprev, const float* __restrict__ bi,
    const float* __restrict__ bh, const ushort_t* __restrict__ wtl,
    float* __restrict__ hout, float* __restrict__ cout,
    ushort_t* __restrict__ hbfout) {
  __shared__ __align__(16) char sL[131072];

  const int tid  = threadIdx.x;
  const int lane = tid & 63;
  const int wid  = tid >> 6;      // 0..7
  const int wm   = wid >> 2;      // 0..1
  const int wn   = wid & 3;       // 0..3
  const int bid  = (blockIdx.x & 7) * 32 + (blockIdx.x >> 3);  // XCD-chunked
  const int bm   = bid & 15;
  const int bn   = bid >> 4;

  const int fr = lane & 15;
  const int oF = lane >> 4;
  const int sw = (oF ^ ((fr >> 1) & 3)) * 16;

  const unsigned sBase = (unsigned)(size_t)&sL[0];
  const unsigned aAddr = sBase + (unsigned)(wm * 16384 + fr * 64 + sw);
  const unsigned bAddr = sBase + (unsigned)(65536 + (wn >> 1) * 16384 +
                                            (wn & 1) * 4096 + fr * 64 + sw);

  // staging source coords
  const int oA = (tid & 3) ^ ((tid >> 3) & 3);
  const size_t aOff0 = (size_t)(bm * 256 + (tid >> 2)) * 1024 + oA * 8;
  const size_t aOff1 = aOff0 + (size_t)128 * 1024;
  const ushort_t* wtBn = wtl + (size_t)bn * 524288;

  f32x4 acc[8][4];
#pragma unroll
  for (int m = 0; m < 8; ++m)
#pragma unroll
    for (int g = 0; g < 4; ++g) acc[m][g] = (f32x4){0.f, 0.f, 0.f, 0.f};

  bf16x8 ar[4][2], br0[2][2], br1[2][2];

#define STAGE_A(PAR, HALF, TT)                                               \
  {                                                                          \
    const ushort_t* s0 =                                                     \
        (((TT) < 16) ? aX : aH) + ((HALF) ? aOff1 : aOff0) + ((TT) & 15) * 64; \
    char* d = sL + (PAR) * 32768 + (HALF) * 16384 + wid * 1024;              \
    GLDS16(s0, d);                                                           \
    GLDS16(s0 + 32, d + 8192);                                               \
  }
#define STAGE_B(PAR, HALF, TT)                                               \
  {                                                                          \
    const ushort_t* s0 =                                                     \
        wtBn + (size_t)((TT) & 31) * 16384 + (HALF) * 8192 + tid * 8;        \
    char* d = sL + 65536 + (PAR) * 32768 + (HALF) * 16384 + wid * 1024;      \
    GLDS16(s0, d);                                                           \
    GLDS16(s0 + 4096, d + 8192);                                             \
  }
// stage cprev quarter Q (64 rows x 64 cols fp32 = 16 KB) to LDS byte QB
#define STAGE_CP(Q, QB)                                                      \
  {                                                                          \
    _Pragma("unroll") for (int c = 0; c < 2; ++c) {                          \
      const int j = c * 512 + tid;                                           \
      const float* s0 = cprev +                                              \
                        (size_t)(bm * 256 + (Q) * 64 + (j >> 4)) * 1024 +    \
                        bn * 64 + (j & 15) * 4;                              \
      GLDS16(s0, sL + (QB) + c * 8192 + wid * 1024);                         \
    }                                                                        \
  }
#define RD_A(PAR, MH)                                                        \
  _Pragma("unroll") for (int mp = 0; mp < 4; ++mp)                           \
      _Pragma("unroll") for (int kh = 0; kh < 2; ++kh)                       \
      ar[mp][kh] = dsr128(aAddr, (PAR) * 32768 + kh * 8192 +                 \
                                     ((MH) * 4 + mp) * 1024);
#define RD_B(PAR, NH, BR)                                                    \
  _Pragma("unroll") for (int gg = 0; gg < 2; ++gg)                           \
      _Pragma("unroll") for (int kh = 0; kh < 2; ++kh)                       \
      BR[gg][kh] = dsr128(bAddr, (PAR) * 32768 + kh * 8192 +                 \
                                     ((NH) * 2 + gg) * 1024);
#define MM(MH, NH, BR)                                                       \
  __builtin_amdgcn_s_setprio(1);                                             \
  _Pragma("unroll") for (int gg = 0; gg < 2; ++gg)                           \
      _Pragma("unroll") for (int mp = 0; mp < 4; ++mp)                       \
      _Pragma("unroll") for (int kh = 0; kh < 2; ++kh)                       \
      acc[(MH) * 4 + mp][(NH) * 2 + gg] =                                    \
          __builtin_amdgcn_mfma_f32_16x16x32_bf16(                           \
              ar[mp][kh], BR[gg][kh], acc[(MH) * 4 + mp][(NH) * 2 + gg],     \
              0, 0, 0);                                                      \
  __builtin_amdgcn_s_setprio(0);

  // ---- prologue: A(0),B(0) then B(1); vmcnt(4) leaves B(1) in flight ----
  STAGE_A(0, 0, 0)
  STAGE_A(0, 1, 0)
  STAGE_B(0, 0, 0)
  STAGE_B(0, 1, 0)
  STAGE_B(1, 0, 1)
  STAGE_B(1, 1, 1)
  WAITV(4)
  BAR()

#pragma unroll 1
  for (int t2 = 0; t2 < 30; t2 += 2) {
    // ---- tile T = t2 (par 0) ----
    RD_A(0, 0) RD_B(0, 0, br0)
    STAGE_A(1, 0, t2 + 1)
    BAR()
    LGKM0()
    MM(0, 0, br0)
    BAR()

    RD_B(0, 1, br1)
    STAGE_A(1, 1, t2 + 1)
    BAR()
    LGKM0()
    MM(0, 1, br1)
    BAR()

    RD_A(0, 1)
    STAGE_B(0, 0, (t2 + 2))
    BAR()
    LGKM0()
    MM(1, 0, br0)
    BAR()

    STAGE_B(0, 1, (t2 + 2))
    BAR()
    MM(1, 1, br1)
    WAITV(4)
    BAR()

    // ---- tile T+1 (par 1) ----
    RD_A(1, 0) RD_B(1, 0, br0)
    STAGE_A(0, 0, (t2 + 2))
    BAR()
    LGKM0()
    MM(0, 0, br0)
    BAR()

    RD_B(1, 1, br1)
    STAGE_A(0, 1, (t2 + 2))
    BAR()
    LGKM0()
    MM(0, 1, br1)
    BAR()

    RD_A(1, 1)
    STAGE_B(1, 0, (t2 + 3))
    BAR()
    LGKM0()
    MM(1, 0, br0)
    BAR()

    STAGE_B(1, 1, (t2 + 3))
    BAR()
    MM(1, 1, br1)
    WAITV(4)
    BAR()
  }

  // ---- peeled final pair: tiles 30 (par0), 31 (par1); cprev into dead LDS ----
  {
    // tile 30
    RD_A(0, 0) RD_B(0, 0, br0)
    STAGE_A(1, 0, 31)
    BAR()
    LGKM0()
    MM(0, 0, br0)
    BAR()

    RD_B(0, 1, br1)
    STAGE_A(1, 1, 31)
    BAR()
    LGKM0()
    MM(0, 1, br1)
    BAR()

    RD_A(0, 1)
    STAGE_CP(0, 65536)        // B[par0] half0 dead after ph2
    BAR()
    LGKM0()
    MM(1, 0, br0)
    BAR()

    STAGE_CP(1, 81920)        // B[par0] half1
    BAR()
    MM(1, 1, br1)
    WAITV(4)                  // queue [B31:4,A31:4,cp:4] -> forces B31+A31
    BAR()

    // tile 31
    RD_A(1, 0) RD_B(1, 0, br0)
    STAGE_CP(2, 0)            // A[par0] half0 dead after tile30 ph3
    BAR()
    LGKM0()
    MM(0, 0, br0)
    BAR()

    RD_B(1, 1, br1)
    STAGE_CP(3, 16384)        // A[par0] half1
    BAR()
    LGKM0()
    MM(0, 1, br1)
    BAR()

    RD_A(1, 1)
    BAR()
    LGKM0()
    MM(1, 0, br0)
    BAR()

    BAR()
    MM(1, 1, br1)
    WAITV(0)                  // all cprev quarters landed
  }
#undef STAGE_A
#undef STAGE_B
#undef STAGE_CP
#undef RD_A
#undef RD_B
#undef MM

  __syncthreads();

  // ---- epilogue: cell from in-LDS cprev image; 3 barriers total ----
  const int hcolL = wn * 16 + fr;              // 0..63
  const int hcol  = bn * 64 + hcolL;
  float bsum[4];
#pragma unroll
  for (int g = 0; g < 4; ++g)
    bsum[g] = bi[g * 1024 + hcol] + bh[g * 1024 + hcol];

  float hv[8][4];
#pragma unroll
  for (int m = 0; m < 8; ++m) {
    const int qbase = (wm ? 0 : 65536) + (m >> 2) * 16384;
    const int rloc  = (m & 3) * 16 + oF * 4;
#pragma unroll
    for (int r = 0; r < 4; ++r) {
      float* cpp = (float*)(sL + qbase + (rloc + r) * 256 + hcolL * 4);
      const float cp = *cpp;
      const float gi = fast_sigmoid(acc[m][0][r] + bsum[0]);
      const float gf = fast_sigmoid(acc[m][1][r] + bsum[1]);
      const float gg = fast_tanh(acc[m][2][r] + bsum[2]);
      const float go = fast_sigmoid(acc[m][3][r] + bsum[3]);
      const float c  = gf * cp + gi * gg;
      *cpp = c;                                  // in-place (owner-exclusive)
      hv[m][r] = go * fast_tanh(c);
    }
  }
  __syncthreads();
  {
    float* co0 = cout + (size_t)(bm * 256) * 1024 + bn * 64;
    const int crow = tid >> 4;                   // 0..31
    const int cb   = (tid & 15) * 16;            // byte col
#pragma unroll
    for (int i = 0; i < 8; ++i) {
      const int row = i * 32 + crow;
      const int ab  = ((row < 128) ? 65536 : 0) + ((row >> 6) & 1) * 16384 +
                      (row & 63) * 256 + cb;
      f32x4 v = *(const f32x4*)(sL + ab);
      *(f32x4*)(co0 + (size_t)row * 1024 + (tid & 15) * 4) = v;
    }
  }
  __syncthreads();
#pragma unroll
  for (int m = 0; m < 8; ++m) {
    const int qbase = (wm ? 0 : 65536) + (m >> 2) * 16384;
    const int rloc  = (m & 3) * 16 + oF * 4;
#pragma unroll
    for (int r = 0; r < 4; ++r)
      *(float*)(sL + qbase + (rloc + r) * 256 + hcolL * 4) = hv[m][r];
  }
  __syncthreads();
  {
    float* ho0 = hout + (size_t)(bm * 256) * 1024 + bn * 64;
    ushort_t* hb0 = hbfout + (size_t)(bm * 256) * 1024 + bn * 64;
    const int crow = tid >> 4;
    const int cb   = (tid & 15) * 16;
#pragma unroll
    for (int i = 0; i < 8; ++i) {
      const int row = i * 32 + crow;
      const int ab  = ((row < 128) ? 65536 : 0) + ((row >> 6) & 1) * 16384 +
                      (row & 63) * 256 + cb;
      f32x4 v = *(const f32x4*)(sL + ab);
      *(f32x4*)(ho0 + (size_t)row * 1024 + (tid & 15) * 4) = v;
      s16x4 hb;
#pragma unroll
      for (int j = 0; j < 4; ++j) hb[j] = (short)f2bf(v[j]);
      *(s16x4*)(hb0 + (size_t)row * 1024 + (tid & 15) * 4) = hb;
    }
  }
}

// ---------------------------------------------------------------------------
// Weight pack (z=0..3) + fc weight transpose (z=4 plane, first 16 T-blocks).
// packW image per (l, bn, T, half): 16 KB [kh 2][pcol 128][slot 4]x16B,
// slot s of pcol r holds octet o = s^((r>>1)&3). t16 padded to 257.
// ---------------------------------------------------------------------------
__global__ __launch_bounds__(512) void packW(const float* __restrict__ Wi,
                                             const float* __restrict__ Wh,
                                             const float* __restrict__ Wfc,
                                             ushort_t* __restrict__ wt,
                                             ushort_t* __restrict__ fcwt) {
  const int bn = blockIdx.x;   // 0..15
  const int T  = blockIdx.y;   // 0..31
  const int l  = blockIdx.z;   // 0..4
  const int tid = threadIdx.x;

  if (l == 4) {                // fc transpose plane
    if (T >= 16) return;
    const int c  = tid & 63;
    const int ko = (tid >> 6) * 8;
    float v[8];
#pragma unroll
    for (int j = 0; j < 8; ++j)
      v[j] = Wfc[(size_t)(T * 64 + ko + j) * 1024 + bn * 64 + c];
    bf16x8 o;
#pragma unroll
    for (int j = 0; j < 8; ++j) o[j] = (short)f2bf(v[j]);
    ushort_t* tile = fcwt + ((size_t)bn * 16 + T) * 4096;
    *(bf16x8*)((char*)tile + swz(c, ko)) = o;
    return;
  }

  __shared__ ushort_t t16[64 * 257];
  const int kq = tid >> 6, cc = tid & 63;
  const int k0 = T * 64;
  const float* W = (k0 < 1024)
                       ? (Wi + (size_t)l * 1024 * 4096 + (size_t)k0 * 4096)
                       : (Wh + (size_t)l * 1024 * 4096 + (size_t)(k0 - 1024) * 4096);
#pragma unroll
  for (int kk = 0; kk < 8; ++kk) {
    const int kl = kq * 8 + kk;
#pragma unroll
    for (int g = 0; g < 4; ++g) {
      const float v = W[(size_t)kl * 4096 + g * 1024 + bn * 64 + cc];
      const int p = (cc >> 4) * 64 + g * 16 + (cc & 15);
      t16[kl * 257 + p] = f2bf(v);
    }
  }
  __syncthreads();
#pragma unroll
  for (int half = 0; half < 2; ++half) {
    ushort_t* img =
        wt + (((size_t)l * 16 + bn) * 32 + T) * 16384 + half * 8192;
#pragma unroll
    for (int c = 0; c < 2; ++c) {
      const int idx = c * 512 + tid;          // chunk 0..1023
      const int kh = idx >> 9;
      const int r  = (idx >> 2) & 127;
      const int s  = idx & 3;
      const int o  = s ^ ((r >> 1) & 3);
      const int klb = kh * 32 + o * 8;
      const int pg  = half * 128 + r;
      bf16x8 ov;
#pragma unroll
      for (int j = 0; j < 8; ++j) ov[j] = (short)t16[(klb + j) * 257 + pg];
      *(bf16x8*)(img + (size_t)idx * 8) = ov;
    }
  }
}

// ---------------------------------------------------------------------------
// FC: y = h3 @ fc_W + fc_b — triple-buffered, counted vmcnt (never drains
// mid-loop except the tail). LDS 72 KB -> 2 blocks/CU.
// ---------------------------------------------------------------------------
__global__ __launch_bounds__(512) void fc_kernel(
    const ushort_t* __restrict__ wtfc, const ushort_t* __restrict__ abf,
    const float* __restrict__ bias, float* __restrict__ y) {
  __shared__ __align__(16) char sA[3][16384];
  __shared__ __align__(16) char sB[3][8192];
  const int tid  = threadIdx.x;
  const int lane = tid & 63;
  const int wid  = tid >> 6;
  const int wm   = wid >> 2;
  const int wn   = wid & 3;
  const int bid  = (blockIdx.x & 7) * 64 + (blockIdx.x >> 3);
  const int bm   = bid & 31;
  const int bn   = bid >> 5;

  f32x4 acc[4];
#pragma unroll
  for (int m = 0; m < 4; ++m) acc[m] = (f32x4){0.f, 0.f, 0.f, 0.f};

  const int rloc = wid * 8 + (lane >> 3);
  const int jA   = (lane & 7) ^ ((lane >> 3) & 7);
  const ushort_t* aSrc = abf + (size_t)(bm * 128 + rloc) * 1024 + jA * 8;

#define FSTAGE(BUF, KS)                                                      \
  {                                                                          \
    GLDS16(wtfc + (size_t)(bn * 16 + (KS)) * 4096 + tid * 8,                 \
           sB[BUF] + wid * 1024);                                            \
    GLDS16(aSrc + (KS) * 64, sA[BUF] + wid * 1024);                          \
    GLDS16(aSrc + (KS) * 64 + 64 * 1024, sA[BUF] + 8192 + wid * 1024);       \
  }

  FSTAGE(0, 0)
  FSTAGE(1, 1)
  WAITV(3)
  BAR()

#pragma unroll
  for (int ks = 0; ks < 16; ++ks) {
    const int cur = ks % 3;
    if (ks + 2 < 16) { FSTAGE((ks + 2) % 3, ks + 2) }
#pragma unroll
    for (int kk = 0; kk < 64; kk += 32) {
      const int ke = kk + (lane >> 4) * 8;
      bf16x8 a[4];
#pragma unroll
      for (int m = 0; m < 4; ++m)
        a[m] = *(const bf16x8*)(sA[cur] +
                                swz(wm * 64 + m * 16 + (lane & 15), ke));
      bf16x8 b = *(const bf16x8*)(sB[cur] + swz(wn * 16 + (lane & 15), ke));
#pragma unroll
      for (int m = 0; m < 4; ++m)
        acc[m] = __builtin_amdgcn_mfma_f32_16x16x32_bf16(a[m], b, acc[m], 0, 0, 0);
    }
    if (ks < 15) {
      if (ks + 2 < 16) { WAITV(3) } else { WAITV(0) }
      BAR()
    }
  }
#undef FSTAGE

  const int col = bn * 64 + wn * 16 + (lane & 15);
  const float bb = bias[col];
#pragma unroll
  for (int m = 0; m < 4; ++m) {
    const int row0 = bm * 128 + wm * 64 + m * 16 + ((lane >> 4) << 2);
#pragma unroll
    for (int r = 0; r < 4; ++r)
      y[(size_t)(row0 + r) * 1024 + col] = acc[m][r] + bb;
  }
}

// fp32 -> bf16 bulk convert for x and hprev in one launch
__global__ __launch_bounds__(256) void cvt_bf16_2(const float* __restrict__ s0,
                                                  unsigned n0,
                                                  const float* __restrict__ s1,
                                                  ushort_t* __restrict__ d0,
                                                  ushort_t* __restrict__ d1,
                                                  unsigned ntot) {
  const unsigned i = blockIdx.x * 256 + threadIdx.x;
  if (i >= ntot) return;
  const float* p;
  ushort_t* d;
  unsigned j;
  if (i < n0) {
    p = s0; d = d0; j = i;
  } else {
    p = s1; d = d1; j = i - n0;
  }
  const float* pp = p + (size_t)j * 8;
  f32x4 a = ((const f32x4*)pp)[0];
  f32x4 b = ((const f32x4*)pp)[1];
  bf16x8 o;
#pragma unroll
  for (int k = 0; k < 4; ++k) {
    o[k]     = (short)f2bf(a[k]);
    o[4 + k] = (short)f2bf(b[k]);
  }
  *(bf16x8*)(d + (size_t)j * 8) = o;
}

extern "C" void kernel_launch(void* const* d_in, const int* in_sizes, int n_in,
                              void* d_out, int out_size, void* d_ws,
                              size_t ws_size, hipStream_t stream) {
  const float* x     = (const float*)d_in[0];
  const float* hprev = (const float*)d_in[1];
  const float* cprev = (const float*)d_in[2];
  const float* Wi    = (const float*)d_in[3];
  const float* Wh    = (const float*)d_in[4];
  const float* bi    = (const float*)d_in[5];
  const float* bh    = (const float*)d_in[6];
  const float* fcW   = (const float*)d_in[7];
  const float* fcb   = (const float*)d_in[8];

  float* out = (float*)d_out;
  const size_t BH = (size_t)B_ * H_;          // 4194304
  float* y    = out;
  float* hout = out + BH;
  float* cout = out + 5 * BH;

  const size_t WT_ELEMS = (size_t)4 * 16 * 32 * 16384;  // 33554432
  const size_t FC_ELEMS = (size_t)16 * 16 * 4096;       // 1048576
  ushort_t* wt      = (ushort_t*)d_ws;
  ushort_t* fcwt    = wt + WT_ELEMS;
  ushort_t* xbf     = fcwt + FC_ELEMS;
  ushort_t* hprevbf = xbf + BH;
  ushort_t* houtbf  = hprevbf + 4 * BH;

  packW<<<dim3(16, 32, 5), dim3(512), 0, stream>>>(Wi, Wh, fcW, wt, fcwt);
  {
    const unsigned n0 = (unsigned)(BH / 8);          // x chunks
    const unsigned n1 = (unsigned)(4 * BH / 8);      // hprev chunks
    const unsigned nt = n0 + n1;
    cvt_bf16_2<<<dim3((nt + 255) / 256), dim3(256), 0, stream>>>(
        x, n0, hprev, xbf, hprevbf, nt);
  }

  for (int l = 0; l < NLAY; ++l) {
    const ushort_t* aX  = (l == 0) ? xbf : (houtbf + (size_t)(l - 1) * BH);
    const ushort_t* wtl = wt + (size_t)l * 16 * 32 * 16384;
    lstm8<<<dim3(256), dim3(512), 0, stream>>>(
        aX, hprevbf + (size_t)l * BH, cprev + (size_t)l * BH, bi + l * 4096,
        bh + l * 4096, wtl, hout + (size_t)l * BH, cout + (size_t)l * BH,
        houtbf + (size_t)l * BH);
  }
  fc_kernel<<<dim3(512), dim3(512), 0, stream>>>(fcwt, houtbf + 3 * BH, fcb, y);
}